// Round 9
// baseline (125.223 us; speedup 1.0000x reference)
//
#include <hip/hip_runtime.h>
#include <hip/hip_fp16.h>
#include <math.h>
#include <string.h>

#define WSZ 11
#define STRIPH 32          // output rows per wave strip
#define WALK 42            // STRIPH + 10
#define NTHREADS 256       // 4 waves per block

struct GWH { unsigned g2[WSZ]; };   // half2-packed taps (same value both halves)

__device__ __forceinline__ unsigned h2u(__half2 h) {
  return __builtin_bit_cast(unsigned, h);
}
__device__ __forceinline__ __half2 u2h(unsigned u) {
  return __builtin_bit_cast(__half2, u);
}

// m1 = mu1, m2 = mu2, mss = E[a^2+b^2], m12 = E[ab]
__device__ __forceinline__ float ssim_px(float m1, float m2, float mss, float m12) {
  const float C1 = 0.0001f, C2 = 0.0009f;
  const float mu1s = m1 * m1, mu2s = m2 * m2, mu12 = m1 * m2;
  const float num = (2.f * mu12 + C1) * (2.f * (m12 - mu12) + C2);
  const float den = (mu1s + mu2s + C1) * (mss - mu1s - mu2s + C2);
  return num * __builtin_amdgcn_rcpf(den);
}

// 14-float window from one image row; clamped offsets + zero masks are
// precomputed per lane (row-invariant).
__device__ __forceinline__ void loadwin(const float* __restrict__ rp,
                                        int o0, int o1, int o2, int o3, int o4,
                                        float m0, float m1, float m3, float m4,
                                        float v[14]) {
  const float f3 = rp[o0];
  const float4 w1 = *(const float4*)(rp + o1);
  const float4 w2 = *(const float4*)(rp + o2);
  const float4 w3 = *(const float4*)(rp + o3);
  const float f16 = rp[o4];
  v[0] = f3 * m0;
  v[1] = w1.x * m1; v[2] = w1.y * m1; v[3] = w1.z * m1; v[4] = w1.w * m1;
  v[5] = w2.x;      v[6] = w2.y;      v[7] = w2.z;      v[8] = w2.w;
  v[9] = w3.x * m3; v[10] = w3.y * m3; v[11] = w3.z * m3; v[12] = w3.w * m3;
  v[13] = f16 * m4;
}

#define G2(K_) u2h(wh.g2[K_])

// One row-step. SM_ = S_ % 11 (literal), JMAX_ = warm-up gate (literal).
#define STEP(SM_, JMAX_, S_)                                                   \
  {                                                                            \
    const int r_ = y0 - 5 + (S_);                                              \
    __half2 hA[4], hS[4];                                                      \
    if ((unsigned)r_ < 512u) {                                                 \
      const float* rp1 = p1 + ((size_t)r_ << 9);                               \
      const float* rp2 = p2 + ((size_t)r_ << 9);                               \
      float a[14], b[14];                                                      \
      loadwin(rp1, o0, o1, o2, o3, o4, m0, m1, m3, m4, a);                     \
      loadwin(rp2, o0, o1, o2, o3, o4, m0, m1, m3, m4, b);                     \
      __half2 vab[14], vsb[14];                                                \
      _Pragma("unroll")                                                        \
      for (int q = 0; q < 14; q++) {                                           \
        vab[q] = __floats2half2_rn(a[q], b[q]);                                \
        vsb[q] = __floats2half2_rn(fmaf(a[q], a[q], b[q] * b[q]),              \
                                   a[q] * b[q]);                               \
      }                                                                        \
      _Pragma("unroll")                                                        \
      for (int x = 0; x < 4; x++) {                                            \
        hA[x] = __hmul2(G2(0), vab[x]);                                        \
        hS[x] = __hmul2(G2(0), vsb[x]);                                        \
      }                                                                        \
      _Pragma("unroll")                                                        \
      for (int k = 1; k < WSZ; k++) {                                          \
        _Pragma("unroll")                                                      \
        for (int x = 0; x < 4; x++) {                                          \
          hA[x] = __hfma2(G2(k), vab[x + k], hA[x]);                           \
          hS[x] = __hfma2(G2(k), vsb[x + k], hS[x]);                           \
        }                                                                      \
      }                                                                        \
    } else {                                                                   \
      _Pragma("unroll")                                                        \
      for (int x = 0; x < 4; x++) { hA[x] = u2h(0u); hS[x] = u2h(0u); }        \
    }                                                                          \
    _Pragma("unroll")                                                          \
    for (int j = 0; j <= 10; j++) {                                            \
      if (j <= (JMAX_)) {                                                      \
        const int sl = ((SM_) + 22 - j) % 11;                                  \
        _Pragma("unroll")                                                      \
        for (int x = 0; x < 4; x++) {                                          \
          rA[sl][x] = __hfma2(G2(j), hA[x], rA[sl][x]);                        \
          rS[sl][x] = __hfma2(G2(j), hS[x], rS[sl][x]);                        \
        }                                                                      \
      }                                                                        \
    }                                                                          \
    if ((S_) >= 10) {                                                          \
      const int se = ((SM_) + 1) % 11;                                         \
      _Pragma("unroll")                                                        \
      for (int x = 0; x < 4; x++) {                                            \
        const float2 u = __half22float2(rA[se][x]);                            \
        const float2 v = __half22float2(rS[se][x]);                            \
        ssimAcc += ssim_px(u.x, u.y, v.x, v.y);                                \
        rA[se][x] = u2h(0u); rS[se][x] = u2h(0u);                              \
      }                                                                        \
    }                                                                          \
  }

__global__ __launch_bounds__(NTHREADS) void ssim_main_kernel(
    const float* __restrict__ img1, const float* __restrict__ img2,
    float* __restrict__ partials, GWH wh)
{
  __shared__ float sred[NTHREADS / 64];

  const int tid = threadIdx.x;
  const int wv = tid >> 6;
  const int lane = tid & 63;

  // strip decode: ys fastest for L2 locality of vertical halo overlap
  const int wid = blockIdx.x * (NTHREADS / 64) + wv;
  const int ys = wid & 15;
  const int xs = (wid >> 4) & 1;
  const int plane = wid >> 5;

  const int y0 = ys * STRIPH;
  const float* __restrict__ p1 = img1 + (size_t)plane * 262144;
  const float* __restrict__ p2 = img2 + (size_t)plane * 262144;

  // per-lane window geometry (row-invariant): Jb = float4 window base
  const int Jb = 64 * xs + lane - 2;
  const int i3 = 4 * Jb + 3;
  const int o0 = i3 < 0 ? 0 : i3;
  const float m0 = i3 < 0 ? 0.f : 1.f;
  const int j1 = Jb + 1;
  const int o1 = 4 * (j1 < 0 ? 0 : j1);
  const float m1 = j1 < 0 ? 0.f : 1.f;
  const int o2 = 4 * (Jb + 2);
  const int j3 = Jb + 3;
  const int o3 = 4 * (j3 > 127 ? 127 : j3);
  const float m3 = j3 > 127 ? 0.f : 1.f;
  const int i16 = 4 * (Jb + 4);
  const int o4 = i16 > 511 ? 511 : i16;
  const float m4 = i16 > 511 ? 0.f : 1.f;

  // 11-slot output ring: per slot 4 px x 2 streams of half2
  __half2 rA[11][4], rS[11][4];
#pragma unroll
  for (int s = 0; s < 11; s++)
#pragma unroll
    for (int x = 0; x < 4; x++) { rA[s][x] = u2h(0u); rS[s][x] = u2h(0u); }

  float ssimAcc = 0.f;

  // warm-up: s = 0..10, ring writes gated to j <= s (no o<0 pollution)
  STEP(0, 0, 0)   STEP(1, 1, 1)   STEP(2, 2, 2)   STEP(3, 3, 3)
  STEP(4, 4, 4)   STEP(5, 5, 5)   STEP(6, 6, 6)   STEP(7, 7, 7)
  STEP(8, 8, 8)   STEP(9, 9, 9)   STEP(10, 10, 10)

  // main: s = 11..32 (sb multiple of 11 keeps slot arithmetic static)
  for (int sb = 11; sb <= 22; sb += 11) {
    STEP(0, 10, sb + 0)  STEP(1, 10, sb + 1)  STEP(2, 10, sb + 2)
    STEP(3, 10, sb + 3)  STEP(4, 10, sb + 4)  STEP(5, 10, sb + 5)
    STEP(6, 10, sb + 6)  STEP(7, 10, sb + 7)  STEP(8, 10, sb + 8)
    STEP(9, 10, sb + 9)  STEP(10, 10, sb + 10)
  }

  // tail: s = 33..41 ungated (writes for o>31 land in never-emitted slots)
  STEP(0, 10, 33)  STEP(1, 10, 34)  STEP(2, 10, 35)  STEP(3, 10, 36)
  STEP(4, 10, 37)  STEP(5, 10, 38)  STEP(6, 10, 39)  STEP(7, 10, 40)
  STEP(8, 10, 41)

  // block reduction
  for (int off = 32; off > 0; off >>= 1)
    ssimAcc += __shfl_down(ssimAcc, off, 64);
  if (lane == 0) sred[wv] = ssimAcc;
  __syncthreads();
  if (tid == 0) {
    float s = 0.f;
#pragma unroll
    for (int i = 0; i < NTHREADS / 64; i++) s += sred[i];
    partials[blockIdx.x] = s;
  }
}

__global__ __launch_bounds__(256) void ssim_final_kernel(
    const float* __restrict__ partials, float* __restrict__ out,
    int n, double invN)
{
  __shared__ double sred[4];
  const int tid = threadIdx.x;
  double s = 0.0;
  for (int i = tid; i < n; i += 256) s += (double)partials[i];
  for (int off = 32; off > 0; off >>= 1)
    s += __shfl_down(s, off, 64);
  if ((tid & 63) == 0) sred[tid >> 6] = s;
  __syncthreads();
  if (tid == 0) {
    double tot = 0.0;
#pragma unroll
    for (int i = 0; i < 4; i++) tot += sred[i];
    out[0] = (float)(1.0 - tot * invN);
  }
}

extern "C" void kernel_launch(void* const* d_in, const int* in_sizes, int n_in,
                              void* d_out, int out_size, void* d_ws, size_t ws_size,
                              hipStream_t stream) {
  const float* img1 = (const float*)d_in[0];
  const float* img2 = (const float*)d_in[1];
  float* out = (float*)d_out;
  float* partials = (float*)d_ws;

  const int planes = in_sizes[0] / (512 * 512);   // 96
  const int nBlocks = planes * 8;                 // 768 (4 strips/block)

  GWH wh;
  {
    double g[WSZ], sum = 0.0;
    for (int i = 0; i < WSZ; i++) {
      const double x = (double)(i - WSZ / 2);
      g[i] = exp(-(x * x) / (2.0 * 1.5 * 1.5));
      sum += g[i];
    }
    for (int i = 0; i < WSZ; i++) {
      const _Float16 hf = (_Float16)(float)(g[i] / sum);
      unsigned short hb;
      memcpy(&hb, &hf, 2);
      wh.g2[i] = (unsigned)hb | ((unsigned)hb << 16);
    }
  }

  const double invN = 1.0 / (double)in_sizes[0];

  ssim_main_kernel<<<nBlocks, NTHREADS, 0, stream>>>(img1, img2, partials, wh);
  ssim_final_kernel<<<1, 256, 0, stream>>>(partials, out, nBlocks, invN);
}

// Round 10
// 84.090 us; speedup vs baseline: 1.4891x; 1.4891x over previous
//
#include <hip/hip_runtime.h>
#include <hip/hip_fp16.h>
#include <math.h>
#include <string.h>

#define WSZ 11
#define TX 64
#define TY 64
#define IN_H 74            // TY + 10
#define SIP 66             // si row stride in uint (half2) units
#define NTHREADS 256

struct GWH { unsigned g2[WSZ]; };   // half2-packed taps

__device__ __forceinline__ unsigned h2u(__half2 h) {
  return __builtin_bit_cast(unsigned, h);
}
__device__ __forceinline__ __half2 u2h(unsigned u) {
  return __builtin_bit_cast(__half2, u);
}

// m1 = mu1, m2 = mu2, mss = E[a^2+b^2], m12 = E[ab]
__device__ __forceinline__ float ssim_px(float m1, float m2, float mss, float m12) {
  const float C1 = 0.0001f, C2 = 0.0009f;
  const float mu1s = m1 * m1, mu2s = m2 * m2, mu12 = m1 * m2;
  const float num = (2.f * mu12 + C1) * (2.f * (m12 - mu12) + C2);
  const float den = (mu1s + mu2s + C1) * (mss - mu1s - mu2s + C2);
  return num * __builtin_amdgcn_rcpf(den);
}

// 18-float window (8 output px) from one image row.
// Offsets (float indices) and masks precomputed per thread (row-invariant).
__device__ __forceinline__ void loadwin18(const float* __restrict__ rp,
                                          int oS0, int oQ1, int oQ2, int oQ3,
                                          int oQ4, int oS1,
                                          float mS0, float mQ1, float mQ4, float mS1,
                                          float v[18]) {
  const float s0 = rp[oS0];
  const float4 q1 = *(const float4*)(rp + oQ1);
  const float4 q2 = *(const float4*)(rp + oQ2);
  const float4 q3 = *(const float4*)(rp + oQ3);
  const float4 q4 = *(const float4*)(rp + oQ4);
  const float s1 = rp[oS1];
  v[0] = s0 * mS0;
  v[1] = q1.x * mQ1;  v[2] = q1.y * mQ1;  v[3] = q1.z * mQ1;  v[4] = q1.w * mQ1;
  v[5] = q2.x;  v[6] = q2.y;  v[7] = q2.z;  v[8] = q2.w;
  v[9] = q3.x;  v[10] = q3.y; v[11] = q3.z; v[12] = q3.w;
  v[13] = q4.x * mQ4; v[14] = q4.y * mQ4; v[15] = q4.z * mQ4; v[16] = q4.w * mQ4;
  v[17] = s1 * mS1;
}

__global__ __launch_bounds__(NTHREADS) void ssim_main_kernel(
    const float* __restrict__ img1, const float* __restrict__ img2,
    float* __restrict__ partials, GWH wh)
{
  // streams: si0 = (a,b), si1 = (a^2+b^2, a*b), half2 per px
  __shared__ __align__(16) unsigned si0[IN_H][SIP];
  __shared__ __align__(16) unsigned si1[IN_H][SIP];
  __shared__ float sred[NTHREADS / 64];

  const int tid = threadIdx.x;

  // tile decode: one tile per block
  int b = blockIdx.x;
  const int tx = b & 7;  b >>= 3;
  const int ty = b & 7;  b >>= 3;
  const float* __restrict__ p1 = img1 + (size_t)b * 262144;
  const float* __restrict__ p2 = img2 + (size_t)b * 262144;
  const int gy0 = ty * TY - 5;

  // packed taps in VGPRs
  __half2 gh[WSZ];
#pragma unroll
  for (int k = 0; k < WSZ; k++) gh[k] = u2h(wh.g2[k]);

  // ---- per-thread h-geometry (jj fixed: items stride 256, 256%8==0) ----
  const int jj = tid & 7;
  const int x0 = tx * TX + 8 * jj;
  const int iS0 = x0 - 5;
  const int oS0 = iS0 < 0 ? 0 : iS0;
  const float mS0 = iS0 < 0 ? 0.f : 1.f;
  const int iQ1 = x0 - 4;
  const int oQ1 = iQ1 < 0 ? 0 : iQ1;
  const float mQ1 = iQ1 < 0 ? 0.f : 1.f;
  const int oQ2 = x0;
  const int oQ3 = x0 + 4;
  const int iQ4 = x0 + 8;
  const int oQ4 = iQ4 > 508 ? 508 : iQ4;
  const float mQ4 = iQ4 > 508 ? 0.f : 1.f;
  const int iS1 = x0 + 12;
  const int oS1 = iS1 > 511 ? 511 : iS1;
  const float mS1 = iS1 > 511 ? 0.f : 1.f;

  // ---- horizontal pass: 8 px per item, 592 items ----
  for (int it = tid; it < IN_H * 8; it += NTHREADS) {
    const int r = it >> 3;
    const int gy = gy0 + r;
    unsigned* w0 = &si0[r][8 * jj];
    unsigned* w1 = &si1[r][8 * jj];
    if ((unsigned)gy < 512u) {
      const float* rp1 = p1 + ((size_t)gy << 9);
      const float* rp2 = p2 + ((size_t)gy << 9);
      float a[18], bb[18];
      loadwin18(rp1, oS0, oQ1, oQ2, oQ3, oQ4, oS1, mS0, mQ1, mQ4, mS1, a);
      loadwin18(rp2, oS0, oQ1, oQ2, oQ3, oQ4, oS1, mS0, mQ1, mQ4, mS1, bb);
      __half2 vab[18], vsb[18];
#pragma unroll
      for (int q = 0; q < 18; q++) {
        vab[q] = __floats2half2_rn(a[q], bb[q]);
        vsb[q] = __floats2half2_rn(fmaf(a[q], a[q], bb[q] * bb[q]), a[q] * bb[q]);
      }
      __half2 hA[8], hS[8];
#pragma unroll
      for (int x = 0; x < 8; x++) {
        hA[x] = __hmul2(gh[0], vab[x]);
        hS[x] = __hmul2(gh[0], vsb[x]);
      }
#pragma unroll
      for (int k = 1; k < WSZ; k++) {
#pragma unroll
        for (int x = 0; x < 8; x++) {
          hA[x] = __hfma2(gh[k], vab[x + k], hA[x]);
          hS[x] = __hfma2(gh[k], vsb[x + k], hS[x]);
        }
      }
      *(uint4*)&w0[0] = make_uint4(h2u(hA[0]), h2u(hA[1]), h2u(hA[2]), h2u(hA[3]));
      *(uint4*)&w0[4] = make_uint4(h2u(hA[4]), h2u(hA[5]), h2u(hA[6]), h2u(hA[7]));
      *(uint4*)&w1[0] = make_uint4(h2u(hS[0]), h2u(hS[1]), h2u(hS[2]), h2u(hS[3]));
      *(uint4*)&w1[4] = make_uint4(h2u(hS[4]), h2u(hS[5]), h2u(hS[6]), h2u(hS[7]));
    } else {
      const uint4 z = make_uint4(0u, 0u, 0u, 0u);
      *(uint4*)&w0[0] = z; *(uint4*)&w0[4] = z;
      *(uint4*)&w1[0] = z; *(uint4*)&w1[4] = z;
    }
  }
  __syncthreads();

  // ---- vertical pass + SSIM: 4x x 4y per thread (256 items) ----
  float accSum = 0.f;
  {
    const int j = tid & 15, yi = tid >> 4;
    const int y0 = 4 * yi;
    __half2 accA[4][4], accS[4][4];  // [y-output][px]
#pragma unroll
    for (int o = 0; o < 4; o++)
#pragma unroll
      for (int p = 0; p < 4; p++) { accA[o][p] = u2h(0u); accS[o][p] = u2h(0u); }
#pragma unroll
    for (int k = 0; k < WSZ + 3; k++) {
      const int rr = y0 + k;
      const uint4 ua = *(const uint4*)&si0[rr][4 * j];
      const uint4 us = *(const uint4*)&si1[rr][4 * j];
      const __half2 va[4] = {u2h(ua.x), u2h(ua.y), u2h(ua.z), u2h(ua.w)};
      const __half2 vs[4] = {u2h(us.x), u2h(us.y), u2h(us.z), u2h(us.w)};
#pragma unroll
      for (int o = 0; o < 4; o++) {
        if (k >= o && k - o < WSZ) {
          const __half2 g2 = gh[k - o];
#pragma unroll
          for (int p = 0; p < 4; p++) {
            accA[o][p] = __hfma2(g2, va[p], accA[o][p]);
            accS[o][p] = __hfma2(g2, vs[p], accS[o][p]);
          }
        }
      }
    }
#pragma unroll
    for (int o = 0; o < 4; o++)
#pragma unroll
      for (int p = 0; p < 4; p++) {
        const float2 mab = __half22float2(accA[o][p]);
        const float2 msb = __half22float2(accS[o][p]);
        accSum += ssim_px(mab.x, mab.y, msb.x, msb.y);
      }
  }

  // ---- block reduction ----
  for (int off = 32; off > 0; off >>= 1)
    accSum += __shfl_down(accSum, off, 64);
  if ((tid & 63) == 0) sred[tid >> 6] = accSum;
  __syncthreads();
  if (tid == 0) {
    float s = 0.f;
#pragma unroll
    for (int i = 0; i < NTHREADS / 64; i++) s += sred[i];
    partials[blockIdx.x] = s;
  }
}

__global__ __launch_bounds__(256) void ssim_final_kernel(
    const float* __restrict__ partials, float* __restrict__ out,
    int n, double invN)
{
  __shared__ double sred[4];
  const int tid = threadIdx.x;
  double s = 0.0;
  for (int i = tid; i < n; i += 256) s += (double)partials[i];
  for (int off = 32; off > 0; off >>= 1)
    s += __shfl_down(s, off, 64);
  if ((tid & 63) == 0) sred[tid >> 6] = s;
  __syncthreads();
  if (tid == 0) {
    double tot = 0.0;
#pragma unroll
    for (int i = 0; i < 4; i++) tot += sred[i];
    out[0] = (float)(1.0 - tot * invN);
  }
}

extern "C" void kernel_launch(void* const* d_in, const int* in_sizes, int n_in,
                              void* d_out, int out_size, void* d_ws, size_t ws_size,
                              hipStream_t stream) {
  const float* img1 = (const float*)d_in[0];
  const float* img2 = (const float*)d_in[1];
  float* out = (float*)d_out;
  float* partials = (float*)d_ws;

  const int planes = in_sizes[0] / (512 * 512);   // 96
  const int nBlocks = planes * 8 * 8;             // 6144, one tile each

  GWH wh;
  {
    double g[WSZ], sum = 0.0;
    for (int i = 0; i < WSZ; i++) {
      const double x = (double)(i - WSZ / 2);
      g[i] = exp(-(x * x) / (2.0 * 1.5 * 1.5));
      sum += g[i];
    }
    for (int i = 0; i < WSZ; i++) {
      const _Float16 hf = (_Float16)(float)(g[i] / sum);
      unsigned short hb;
      memcpy(&hb, &hf, 2);
      wh.g2[i] = (unsigned)hb | ((unsigned)hb << 16);
    }
  }

  const double invN = 1.0 / (double)in_sizes[0];

  ssim_main_kernel<<<nBlocks, NTHREADS, 0, stream>>>(img1, img2, partials, wh);
  ssim_final_kernel<<<1, 256, 0, stream>>>(partials, out, nBlocks, invN);
}